// Round 13
// baseline (108.316 us; speedup 1.0000x reference)
//
#include <hip/hip_runtime.h>

#define DD 256
#define DD2 (DD * DD)
#define DD3 (DD * DD * DD)
#define TH 20   // sponge thickness

typedef float f32x4 __attribute__((ext_vector_type(4)));

__device__ __forceinline__ f32x4 ld4_sum(const float* __restrict__ p,
                                         const float* __restrict__ s,
                                         int idx) {
    return *reinterpret_cast<const f32x4*>(p + idx) +
           *reinterpret_cast<const f32x4*>(s + idx);
}

__device__ __forceinline__ f32x4 rcp4(f32x4 x) {
    f32x4 r;
    r.x = __builtin_amdgcn_rcpf(x.x);
    r.y = __builtin_amdgcn_rcpf(x.y);
    r.z = __builtin_amdgcn_rcpf(x.z);
    r.w = __builtin_amdgcn_rcpf(x.w);
    return r;
}

// sigma(x,y,z) = sigma0 * (1 - mind/TH)^2 for mind<TH else 0 (exact per the
// reference's _build_sigma). sigma0 read from sg at (0,128,128) where mind==0.
__device__ __forceinline__ float sigma_at(float sigma0, int mind) {
    if (mind >= TH) return 0.0f;
    const float t = 1.0f - (float)mind / (float)TH;
    return sigma0 * (t * t);
}

__device__ __forceinline__ f32x4 sigma_row(float sigma0, int dxy, int z0) {
    if (dxy >= TH && z0 >= TH && z0 + 3 < DD - TH) return (f32x4)(0.0f);
    f32x4 s;
#pragma unroll
    for (int c = 0; c < 4; ++c) {
        const int z = z0 + c;
        const int mind = min(dxy, min(z, DD - 1 - z));
        s[c] = sigma_at(sigma0, mind);
    }
    return s;
}

// x-pair retry with R9's y-geometry: block = 4 waves, wave = full z-line
// (64 lanes x f4); thread = 4 y-rows x TWO adjacent x-planes. Center planes
// serve as each other's x-neighbor from REGISTERS (halo only at x0-1/x0+2):
// load lines/output 9 -> 7. vs R11: 16-row ytiles (same as R9) and all three
// load groups hoisted (R11's VGPR=64 showed the compiler sank them).
__global__ __launch_bounds__(256) void sponge_kernel(
    const float* __restrict__ src,
    const float* __restrict__ pc,
    const float* __restrict__ pp,
    const float* __restrict__ aa,
    const float* __restrict__ sg,
    const float* __restrict__ dtp,
    float* __restrict__ out_pnew,
    float* __restrict__ out_pcur)
{
    const float dt = dtp[0];
    const float sigma0 = sg[128 * DD + 128];

    const int lane = threadIdx.x & 63;        // z = lane*4
    const int w    = threadIdx.x >> 6;        // wave 0..3

    // 2048 blocks; bijective XCD swizzle (256 per XCD = 16 x-pairs x 16
    // ytiles -> each XCD owns a contiguous 32-plane slab, same as R9).
    const int wid   = (blockIdx.x & 7) * 256 + (blockIdx.x >> 3);
    const int ytile = wid & 15;                // 0..15 (16 rows each)
    const int xpair = wid >> 4;                // 0..127
    const int y0    = ytile * 16 + w * 4;      // this thread: rows y0..y0+3
    const int x0    = xpair * 2;               // planes x0, x0+1
    const int basez = lane * 4;

    const int iA = x0 * DD2 + basez;           // plane A = x0
    const int iB = iA + DD2;                   // plane B = x0+1

    // ---- 1) single-touch HBM streams first (longest latency, NT) ----
    f32x4 pA[4], aA[4], pB[4], aB[4];
#pragma unroll
    for (int r = 0; r < 4; ++r) {
        const int row = (y0 + r) * DD;
        pA[r] = __builtin_nontemporal_load(reinterpret_cast<const f32x4*>(pp + iA + row));
        aA[r] = __builtin_nontemporal_load(reinterpret_cast<const f32x4*>(aa + iA + row));
        pB[r] = __builtin_nontemporal_load(reinterpret_cast<const f32x4*>(pp + iB + row));
        aB[r] = __builtin_nontemporal_load(reinterpret_cast<const f32x4*>(aa + iB + row));
    }

    // ---- 2) x-halo rows (x0-1, x0+2), zero at x faces ----
    f32x4 xm[4], xp[4];
#pragma unroll
    for (int r = 0; r < 4; ++r) {
        const int row = (y0 + r) * DD;
        xm[r] = (f32x4)(0.0f);
        xp[r] = (f32x4)(0.0f);
        if (x0 > 0)      xm[r] = ld4_sum(pc, src, iA - DD2 + row);
        if (x0 + 2 < DD) xp[r] = ld4_sum(pc, src, iB + DD2 + row);
    }

    // ---- 3) center u columns: rows y0-1 .. y0+4 on both planes ----
    f32x4 cA[6], cB[6];
#pragma unroll
    for (int r = 0; r < 6; ++r) {
        const int yy = y0 - 1 + r;
        cA[r] = (f32x4)(0.0f);
        cB[r] = (f32x4)(0.0f);
        if (yy >= 0 && yy < DD) {
            cA[r] = ld4_sum(pc, src, iA + yy * DD);
            cB[r] = ld4_sum(pc, src, iB + yy * DD);
        }
    }

    // ---- 4) sigma: analytic, both planes ----
    const int dxA = min(x0, DD - 1 - x0);
    const int dxB = min(x0 + 1, DD - 2 - x0);
    f32x4 sA[4], sB[4];
#pragma unroll
    for (int r = 0; r < 4; ++r) {
        const int yy = y0 + r;
        const int dy = min(yy, DD - 1 - yy);
        sA[r] = sigma_row(sigma0, min(dxA, dy), basez);
        sB[r] = sigma_row(sigma0, min(dxB, dy), basez);
    }

    // ---- 5) compute + store (plane A then plane B, 4 rows each) ----
#pragma unroll
    for (int r = 0; r < 4; ++r) {
        const int row = (y0 + r) * DD;

        {   // plane A: y = cA[r], cA[r+2]; x = xm[r], cB[r+1]
            const f32x4 u = cA[r + 1];
            float left  = __shfl_up(u.w, 1);
            float right = __shfl_down(u.x, 1);
            if (lane == 0)  left  = 0.0f;
            if (lane == 63) right = 0.0f;

            f32x4 lap;
            lap.x = left  + u.y + cA[r].x + cA[r + 2].x + xm[r].x + cB[r + 1].x - 6.0f * u.x;
            lap.y = u.x   + u.z + cA[r].y + cA[r + 2].y + xm[r].y + cB[r + 1].y - 6.0f * u.y;
            lap.z = u.y   + u.w + cA[r].z + cA[r + 2].z + xm[r].z + cB[r + 1].z - 6.0f * u.z;
            lap.w = u.z   + right + cA[r].w + cA[r + 2].w + xm[r].w + cB[r + 1].w - 6.0f * u.w;

            const f32x4 half = (0.5f * dt) * sA[r];
            const f32x4 num  = 2.0f * u - (1.0f - half) * pA[r] + aA[r] * lap;
            const f32x4 pn   = num * rcp4(1.0f + half);

            __builtin_nontemporal_store(pn, reinterpret_cast<f32x4*>(out_pnew + iA + row));
            __builtin_nontemporal_store(u,  reinterpret_cast<f32x4*>(out_pcur + iA + row));
        }
        {   // plane B: y = cB[r], cB[r+2]; x = cA[r+1], xp[r]
            const f32x4 u = cB[r + 1];
            float left  = __shfl_up(u.w, 1);
            float right = __shfl_down(u.x, 1);
            if (lane == 0)  left  = 0.0f;
            if (lane == 63) right = 0.0f;

            f32x4 lap;
            lap.x = left  + u.y + cB[r].x + cB[r + 2].x + cA[r + 1].x + xp[r].x - 6.0f * u.x;
            lap.y = u.x   + u.z + cB[r].y + cB[r + 2].y + cA[r + 1].y + xp[r].y - 6.0f * u.y;
            lap.z = u.y   + u.w + cB[r].z + cB[r + 2].z + cA[r + 1].z + xp[r].z - 6.0f * u.z;
            lap.w = u.z   + right + cB[r].w + cB[r + 2].w + cA[r + 1].w + xp[r].w - 6.0f * u.w;

            const f32x4 half = (0.5f * dt) * sB[r];
            const f32x4 num  = 2.0f * u - (1.0f - half) * pB[r] + aB[r] * lap;
            const f32x4 pn   = num * rcp4(1.0f + half);

            __builtin_nontemporal_store(pn, reinterpret_cast<f32x4*>(out_pnew + iB + row));
            __builtin_nontemporal_store(u,  reinterpret_cast<f32x4*>(out_pcur + iB + row));
        }
    }
}

extern "C" void kernel_launch(void* const* d_in, const int* in_sizes, int n_in,
                              void* d_out, int out_size, void* d_ws, size_t ws_size,
                              hipStream_t stream) {
    const float* src = (const float*)d_in[0];
    const float* pc  = (const float*)d_in[1];
    const float* pp  = (const float*)d_in[2];
    const float* aa  = (const float*)d_in[3];
    const float* sg  = (const float*)d_in[4];
    const float* dtp = (const float*)d_in[5];
    float* out = (float*)d_out;

    // 128 x-pairs x 16 y-tiles = 2048 blocks (divisible by 8)
    const int grid = 2048;
    sponge_kernel<<<grid, 256, 0, stream>>>(src, pc, pp, aa, sg, dtp,
                                            out, out + DD3);
}

// Round 14
// 88.576 us; speedup vs baseline: 1.2229x; 1.2229x over previous
//
#include <hip/hip_runtime.h>

#define DD 256
#define DD2 (DD * DD)
#define DD3 (DD * DD * DD)
#define TH 20    // sponge thickness

#define XT 4         // output planes per block
#define YT 8         // output rows per block
#define LXP (XT + 2) // staged planes (with x halo)
#define LYP (YT + 2) // staged rows (with y halo)

typedef float f32x4 __attribute__((ext_vector_type(4)));

__device__ __forceinline__ f32x4 ld4_sum(const float* __restrict__ p,
                                         const float* __restrict__ s,
                                         int idx) {
    return *reinterpret_cast<const f32x4*>(p + idx) +
           *reinterpret_cast<const f32x4*>(s + idx);
}

__device__ __forceinline__ f32x4 rcp4(f32x4 x) {
    f32x4 r;
    r.x = __builtin_amdgcn_rcpf(x.x);
    r.y = __builtin_amdgcn_rcpf(x.y);
    r.z = __builtin_amdgcn_rcpf(x.z);
    r.w = __builtin_amdgcn_rcpf(x.w);
    return r;
}

// sigma(x,y,z) = sigma0*(1-mind/TH)^2 for mind<TH else 0 (exact per the
// reference). sigma0 read from sg at (0,128,128) where mind==0.
__device__ __forceinline__ float sigma_at(float sigma0, int mind) {
    if (mind >= TH) return 0.0f;
    const float t = 1.0f - (float)mind / (float)TH;
    return sigma0 * (t * t);
}

__device__ __forceinline__ f32x4 sigma_row(float sigma0, int dxy, int z0) {
    if (dxy >= TH && z0 >= TH && z0 + 3 < DD - TH) return (f32x4)(0.0f);
    f32x4 s;
#pragma unroll
    for (int c = 0; c < 4; ++c) {
        const int z = z0 + c;
        const int mind = min(dxy, min(z, DD - 1 - z));
        s[c] = sigma_at(sigma0, mind);
    }
    return s;
}

// LDS-staged tile: block = 4 waves; tile = 4 planes x 8 rows x full z.
// u = pc+src staged ONCE into LDS (6x10x256 f32 = 60 KB incl. halo);
// each wave computes one plane with all 5 stencil neighbors read from LDS
// (z via shfl). Global u-load slots/row: ~9 -> 3.75, with NO per-thread
// register-state inflation (R7/R8/R13 law). 2 blocks/CU co-resident ->
// one block's staging overlaps the other's compute. NT pp/aa + NT stores.
__global__ __launch_bounds__(256) void sponge_kernel(
    const float* __restrict__ src,
    const float* __restrict__ pc,
    const float* __restrict__ pp,
    const float* __restrict__ aa,
    const float* __restrict__ sg,
    const float* __restrict__ dtp,
    float* __restrict__ out_pnew,
    float* __restrict__ out_pcur)
{
    __shared__ float lds_u[LXP * LYP * DD];   // 61440 B

    const float dt = dtp[0];
    const float sigma0 = sg[128 * DD + 128];

    const int lane = threadIdx.x & 63;        // z = lane*4
    const int w    = threadIdx.x >> 6;        // wave 0..3 -> plane x0+w

    // 2048 blocks; bijective XCD swizzle (256 per XCD). ytile fast ->
    // each XCD owns 8 contiguous x-groups (32-plane slab).
    const int wid   = (blockIdx.x & 7) * 256 + (blockIdx.x >> 3);
    const int ytile = wid & 31;                // 0..31
    const int xg    = wid >> 5;                // 0..63
    const int y0t   = ytile * YT;              // first output row
    const int x0    = xg * XT;                 // first output plane
    const int basez = lane * 4;

    const int gx = x0 + w;                     // this wave's plane

    // ---- 1) NT single-touch streams for this wave's 8 rows (issued first;
    //         complete while we stage + wait at the barrier) ----
    f32x4 p4v[YT], a4v[YT];
#pragma unroll
    for (int r = 0; r < YT; ++r) {
        const int idx = gx * DD2 + (y0t + r) * DD + basez;
        p4v[r] = __builtin_nontemporal_load(reinterpret_cast<const f32x4*>(pp + idx));
        a4v[r] = __builtin_nontemporal_load(reinterpret_cast<const f32x4*>(aa + idx));
    }

    // ---- 2) cooperative staging: 60 plane-rows of u = pc+src ----
#pragma unroll
    for (int i = 0; i < (LXP * LYP) / 4; ++i) {   // 15 per wave
        const int s   = w * ((LXP * LYP) / 4) + i; // 0..59
        const int xi  = s / LYP;
        const int yi  = s - xi * LYP;
        const int gxs = x0 - 1 + xi;
        const int gys = y0t - 1 + yi;
        f32x4 v = (f32x4)(0.0f);
        if (gxs >= 0 && gxs < DD && gys >= 0 && gys < DD)
            v = ld4_sum(pc, src, gxs * DD2 + gys * DD + basez);
        *reinterpret_cast<f32x4*>(&lds_u[s * DD + basez]) = v;
    }
    __syncthreads();

    // ---- 3) compute 8 rows from LDS ----
    const int lpc = (w + 1) * LYP;             // lds plane-row base (center)
    const int dxg = min(gx, DD - 1 - gx);
#pragma unroll
    for (int r = 0; r < YT; ++r) {
        const int gy = y0t + r;

        const f32x4 u   = *reinterpret_cast<const f32x4*>(&lds_u[(lpc + r + 1) * DD + basez]);
        const f32x4 uym = *reinterpret_cast<const f32x4*>(&lds_u[(lpc + r) * DD + basez]);
        const f32x4 uyp = *reinterpret_cast<const f32x4*>(&lds_u[(lpc + r + 2) * DD + basez]);
        const f32x4 uxm = *reinterpret_cast<const f32x4*>(&lds_u[(lpc - LYP + r + 1) * DD + basez]);
        const f32x4 uxp = *reinterpret_cast<const f32x4*>(&lds_u[(lpc + LYP + r + 1) * DD + basez]);

        // z neighbors via cross-lane shuffle; lane edges == grid z faces
        float left  = __shfl_up(u.w, 1);
        float right = __shfl_down(u.x, 1);
        if (lane == 0)  left  = 0.0f;
        if (lane == 63) right = 0.0f;

        f32x4 lap;
        lap.x = left + u.y + uym.x + uyp.x + uxm.x + uxp.x - 6.0f * u.x;
        lap.y = u.x  + u.z + uym.y + uyp.y + uxm.y + uxp.y - 6.0f * u.y;
        lap.z = u.y  + u.w + uym.z + uyp.z + uxm.z + uxp.z - 6.0f * u.z;
        lap.w = u.z  + right + uym.w + uyp.w + uxm.w + uxp.w - 6.0f * u.w;

        const f32x4 s4   = sigma_row(sigma0, min(dxg, min(gy, DD - 1 - gy)), basez);
        const f32x4 half = (0.5f * dt) * s4;
        const f32x4 num  = 2.0f * u - (1.0f - half) * p4v[r] + a4v[r] * lap;
        const f32x4 pn   = num * rcp4(1.0f + half);

        const int idx = gx * DD2 + gy * DD + basez;
        __builtin_nontemporal_store(pn, reinterpret_cast<f32x4*>(out_pnew + idx));
        __builtin_nontemporal_store(u,  reinterpret_cast<f32x4*>(out_pcur + idx));
    }
}

extern "C" void kernel_launch(void* const* d_in, const int* in_sizes, int n_in,
                              void* d_out, int out_size, void* d_ws, size_t ws_size,
                              hipStream_t stream) {
    const float* src = (const float*)d_in[0];
    const float* pc  = (const float*)d_in[1];
    const float* pp  = (const float*)d_in[2];
    const float* aa  = (const float*)d_in[3];
    const float* sg  = (const float*)d_in[4];
    const float* dtp = (const float*)d_in[5];
    float* out = (float*)d_out;

    // 64 x-groups x 32 y-tiles = 2048 blocks (divisible by 8)
    const int grid = 2048;
    sponge_kernel<<<grid, 256, 0, stream>>>(src, pc, pp, aa, sg, dtp,
                                            out, out + DD3);
}